// Round 1
// baseline (238.367 us; speedup 1.0000x reference)
//
#include <hip/hip_runtime.h>
#include <hip/hip_bf16.h>

typedef __attribute__((ext_vector_type(8))) unsigned short ushort8;
typedef __attribute__((ext_vector_type(8))) __bf16 bf16x8;
typedef __attribute__((ext_vector_type(4))) float f32x4;
typedef __attribute__((ext_vector_type(4))) float floatx4;

__device__ __forceinline__ unsigned short f2bf(float f) {
    unsigned u = __builtin_bit_cast(unsigned, f);
    u += 0x7fffu + ((u >> 16) & 1u);   // RNE
    return (unsigned short)(u >> 16);
}
__device__ __forceinline__ float bf2f(unsigned short h) {
    unsigned u = ((unsigned)h) << 16;
    return __builtin_bit_cast(float, u);
}

__device__ __forceinline__ void gload_lds16(const void* g, void* l) {
    __builtin_amdgcn_global_load_lds(
        (const __attribute__((address_space(1))) void*)g,
        (__attribute__((address_space(3))) void*)l,
        16, 0, 0);
}

// ---------------- f32 -> bf16 conversion (8 elems/thread) ----------------
__global__ __launch_bounds__(256) void cvt_f2bf(const float* __restrict__ in,
                                                unsigned short* __restrict__ out,
                                                int n8) {
    int i = blockIdx.x * 256 + threadIdx.x;
    if (i >= n8) return;
    floatx4 a = ((const floatx4*)in)[2 * i];
    floatx4 b = ((const floatx4*)in)[2 * i + 1];
    ushort8 o;
#pragma unroll
    for (int j = 0; j < 4; ++j) { o[j] = f2bf(a[j]); o[4 + j] = f2bf(b[j]); }
    ((ushort8*)out)[i] = o;
}

// ---------------- Weff[o][j] = g[j]*fcW[o][j] + g[j+2048]*fcW[o][j+2048] ----
// cc[o] = fc_b[o] + sum_j ln_b[j]*fcW[o][j] + ln_b[j+2048]*fcW[o][j+2048]
__global__ __launch_bounds__(256) void weff_kernel(const float* __restrict__ fcW,
                                                   const float* __restrict__ lng,
                                                   const float* __restrict__ lnb,
                                                   const float* __restrict__ fcb,
                                                   unsigned short* __restrict__ weff,
                                                   float* __restrict__ cc) {
    int o = blockIdx.x;
    int tid = threadIdx.x;
    if (o >= 1000) {  // pad rows 1000..1023 with zeros
        ushort8 z = {0, 0, 0, 0, 0, 0, 0, 0};
        ((ushort8*)(weff + (size_t)o * 2048))[tid] = z;
        if (tid == 0) cc[o] = 0.f;
        return;
    }
    const float* wrow = fcW + (size_t)o * 4096;
    int j0 = tid * 8;
    floatx4 wa  = *(const floatx4*)(wrow + j0);
    floatx4 wb  = *(const floatx4*)(wrow + j0 + 4);
    floatx4 wa2 = *(const floatx4*)(wrow + 2048 + j0);
    floatx4 wb2 = *(const floatx4*)(wrow + 2048 + j0 + 4);
    floatx4 ga  = *(const floatx4*)(lng + j0);
    floatx4 gb  = *(const floatx4*)(lng + j0 + 4);
    floatx4 ga2 = *(const floatx4*)(lng + 2048 + j0);
    floatx4 gb2 = *(const floatx4*)(lng + 2048 + j0 + 4);
    floatx4 ba  = *(const floatx4*)(lnb + j0);
    floatx4 bb  = *(const floatx4*)(lnb + j0 + 4);
    floatx4 ba2 = *(const floatx4*)(lnb + 2048 + j0);
    floatx4 bb2 = *(const floatx4*)(lnb + 2048 + j0 + 4);
    ushort8 o8;
    float acc = 0.f;
#pragma unroll
    for (int j = 0; j < 4; ++j) {
        o8[j] = f2bf(ga[j] * wa[j] + ga2[j] * wa2[j]);
        acc += ba[j] * wa[j] + ba2[j] * wa2[j];
        o8[4 + j] = f2bf(gb[j] * wb[j] + gb2[j] * wb2[j]);
        acc += bb[j] * wb[j] + bb2[j] * wb2[j];
    }
    ((ushort8*)(weff + (size_t)o * 2048))[tid] = o8;
#pragma unroll
    for (int d = 32; d; d >>= 1) acc += __shfl_down(acc, d);
    __shared__ float red[4];
    if ((tid & 63) == 0) red[tid >> 6] = acc;
    __syncthreads();
    if (tid == 0) cc[o] = fcb[o] + red[0] + red[1] + red[2] + red[3];
}

// ---------------- row LayerNorm stats + z = (h2-mu)*rsqrt(var+eps) ---------
__global__ __launch_bounds__(256) void ln_kernel(const unsigned short* __restrict__ h2,
                                                 unsigned short* __restrict__ z) {
    int row = blockIdx.x, tid = threadIdx.x;
    ushort8 v = ((const ushort8*)(h2 + (size_t)row * 2048))[tid];
    float f[8];
    float s = 0.f, s2 = 0.f;
#pragma unroll
    for (int j = 0; j < 8; ++j) { f[j] = bf2f(v[j]); s += f[j]; s2 += f[j] * f[j]; }
#pragma unroll
    for (int d = 32; d; d >>= 1) { s += __shfl_down(s, d); s2 += __shfl_down(s2, d); }
    __shared__ float rs_[4], rs2_[4];
    if ((tid & 63) == 0) { rs_[tid >> 6] = s; rs2_[tid >> 6] = s2; }
    __syncthreads();
    float S = rs_[0] + rs_[1] + rs_[2] + rs_[3];
    float S2 = rs2_[0] + rs2_[1] + rs2_[2] + rs2_[3];
    float mu = S * (1.f / 2048.f);
    float var = S2 * (1.f / 2048.f) - mu * mu;
    float r = rsqrtf(var + 1e-5f);
    ushort8 o;
#pragma unroll
    for (int j = 0; j < 8; ++j) o[j] = f2bf((f[j] - mu) * r);
    ((ushort8*)(z + (size_t)row * 2048))[tid] = o;
}

// ---------------- bf16 GEMM: C[M,N] = A[M,K] * B[N,K]^T (+epilogue) --------
// EPI 0: out bf16 = tanh(acc + bias0[n] + bias1[n]), stride N
// EPI 1: out f32  = acc + bias0[n], stride ncols, guarded col < ncols
template <int EPI>
__global__ __launch_bounds__(256) void gemm_bt(const unsigned short* __restrict__ A,
                                               const unsigned short* __restrict__ B,
                                               int M, int N, int K,
                                               const float* __restrict__ bias0,
                                               const float* __restrict__ bias1,
                                               void* __restrict__ Cout, int ncols) {
    __shared__ unsigned short As[2][128 * 32];
    __shared__ unsigned short Bs[2][128 * 32];
    const int tid = threadIdx.x, lane = tid & 63, wid = tid >> 6;
    const int wr = wid >> 1, wc = wid & 1;
    const int fr = lane & 15, fk = (lane >> 4) * 8;
    const int row0 = blockIdx.y * 128, col0 = blockIdx.x * 128;

    f32x4 acc[4][4];
#pragma unroll
    for (int m = 0; m < 4; ++m)
#pragma unroll
        for (int n = 0; n < 4; ++n) acc[m][n] = f32x4{0.f, 0.f, 0.f, 0.f};

    const int c0 = wid * 128 + lane;        // chunk id, u=0
    const int r0_ = c0 >> 2, cc0 = (c0 & 3) * 8;
    const int c1 = c0 + 64;                 // chunk id, u=1
    const int r1_ = c1 >> 2, cc1 = (c1 & 3) * 8;

    auto stage = [&](int buf, int kt) {
        const int k0 = kt * 32;
        gload_lds16(A + (size_t)(row0 + r0_) * K + k0 + cc0, &As[buf][wid * 1024]);
        gload_lds16(A + (size_t)(row0 + r1_) * K + k0 + cc1, &As[buf][wid * 1024 + 512]);
        gload_lds16(B + (size_t)(col0 + r0_) * K + k0 + cc0, &Bs[buf][wid * 1024]);
        gload_lds16(B + (size_t)(col0 + r1_) * K + k0 + cc1, &Bs[buf][wid * 1024 + 512]);
    };

    const int NK = K >> 5;
    stage(0, 0);
    for (int kt = 0; kt < NK; ++kt) {
        __syncthreads();  // drains the async loads staged last iteration
        if (kt + 1 < NK) stage((kt + 1) & 1, kt + 1);
        const unsigned short* as = As[kt & 1];
        const unsigned short* bs = Bs[kt & 1];
        bf16x8 af[4], bfr[4];
#pragma unroll
        for (int m = 0; m < 4; ++m) {
            ushort8 raw = *(const ushort8*)(as + (wr * 64 + m * 16 + fr) * 32 + fk);
            af[m] = __builtin_bit_cast(bf16x8, raw);
        }
#pragma unroll
        for (int n = 0; n < 4; ++n) {
            ushort8 raw = *(const ushort8*)(bs + (wc * 64 + n * 16 + fr) * 32 + fk);
            bfr[n] = __builtin_bit_cast(bf16x8, raw);
        }
#pragma unroll
        for (int m = 0; m < 4; ++m)
#pragma unroll
            for (int n = 0; n < 4; ++n)
                acc[m][n] = __builtin_amdgcn_mfma_f32_16x16x32_bf16(af[m], bfr[n], acc[m][n], 0, 0, 0);
    }

#pragma unroll
    for (int m = 0; m < 4; ++m) {
        int rbase = row0 + wr * 64 + m * 16 + (lane >> 4) * 4;
#pragma unroll
        for (int n = 0; n < 4; ++n) {
            int col = col0 + wc * 64 + n * 16 + fr;
            if (EPI == 0) {
                float b = bias0[col] + bias1[col];
                unsigned short* O = (unsigned short*)Cout;
#pragma unroll
                for (int r = 0; r < 4; ++r)
                    O[(size_t)(rbase + r) * N + col] = f2bf(tanhf(acc[m][n][r] + b));
            } else {
                float b = bias0[col];
                float* O = (float*)Cout;
                if (col < ncols) {
#pragma unroll
                    for (int r = 0; r < 4; ++r)
                        O[(size_t)(rbase + r) * ncols + col] = acc[m][n][r] + b;
                }
            }
        }
    }
}

extern "C" void kernel_launch(void* const* d_in, const int* in_sizes, int n_in,
                              void* d_out, int out_size, void* d_ws, size_t ws_size,
                              hipStream_t stream) {
    const float* x   = (const float*)d_in[0];
    const float* W0  = (const float*)d_in[1];
    const float* bi0 = (const float*)d_in[2];
    const float* bh0 = (const float*)d_in[3];
    const float* W1  = (const float*)d_in[4];
    const float* bi1 = (const float*)d_in[5];
    const float* bh1 = (const float*)d_in[6];
    const float* lng = (const float*)d_in[7];
    const float* lnb = (const float*)d_in[8];
    const float* fcW = (const float*)d_in[9];
    const float* fcb = (const float*)d_in[10];
    float* out = (float*)d_out;

    char* w = (char*)d_ws;
    unsigned short* xb   = (unsigned short*)(w);                  // 4096x4096 bf16
    unsigned short* w0b  = (unsigned short*)(w + 33554432ull);    // 2048x4096 bf16
    unsigned short* w1b  = (unsigned short*)(w + 50331648ull);    // 2048x2048 bf16
    unsigned short* h1   = (unsigned short*)(w + 58720256ull);    // 4096x2048 bf16
    unsigned short* h2   = (unsigned short*)(w + 75497472ull);    // 4096x2048 bf16
    unsigned short* zb   = (unsigned short*)(w + 92274688ull);    // 4096x2048 bf16
    unsigned short* weff = (unsigned short*)(w + 109051904ull);   // 1024x2048 bf16
    float* cc            = (float*)(w + 113246208ull);            // 1024 f32

    cvt_f2bf<<<8192, 256, 0, stream>>>(x,  xb,  2097152);
    cvt_f2bf<<<4096, 256, 0, stream>>>(W0, w0b, 1048576);
    cvt_f2bf<<<2048, 256, 0, stream>>>(W1, w1b, 524288);
    weff_kernel<<<1024, 256, 0, stream>>>(fcW, lng, lnb, fcb, weff, cc);
    // h1 = tanh(x @ W0^T + b_ih0 + b_hh0)
    gemm_bt<0><<<dim3(16, 32), 256, 0, stream>>>(xb, w0b, 4096, 2048, 4096, bi0, bh0, h1, 2048);
    // h2 = tanh(h1 @ W1^T + b_ih1 + b_hh1)
    gemm_bt<0><<<dim3(16, 32), 256, 0, stream>>>(h1, w1b, 4096, 2048, 2048, bi1, bh1, h2, 2048);
    // z = (h2 - mu) * rsqrt(var + eps)
    ln_kernel<<<4096, 256, 0, stream>>>(h2, zb);
    // out = z @ Weff^T + cc   (N padded to 1024, stores guarded to 1000)
    gemm_bt<1><<<dim3(8, 32), 256, 0, stream>>>(zb, weff, 4096, 1024, 2048, cc, nullptr, out, 1000);
}

// Round 2
// 199.999 us; speedup vs baseline: 1.1918x; 1.1918x over previous
//
#include <hip/hip_runtime.h>
#include <hip/hip_bf16.h>

typedef __attribute__((ext_vector_type(8))) unsigned short ushort8;
typedef __attribute__((ext_vector_type(8))) __bf16 bf16x8;
typedef __attribute__((ext_vector_type(4))) float f32x4;
typedef __attribute__((ext_vector_type(4))) float floatx4;

__device__ __forceinline__ unsigned short f2bf(float f) {
    unsigned u = __builtin_bit_cast(unsigned, f);
    u += 0x7fffu + ((u >> 16) & 1u);   // RNE
    return (unsigned short)(u >> 16);
}
__device__ __forceinline__ float bf2f(unsigned short h) {
    unsigned u = ((unsigned)h) << 16;
    return __builtin_bit_cast(float, u);
}

__device__ __forceinline__ void gload_lds16(const void* g, void* l) {
    __builtin_amdgcn_global_load_lds(
        (const __attribute__((address_space(1))) void*)g,
        (__attribute__((address_space(3))) void*)l,
        16, 0, 0);
}

#define BAR()      asm volatile("s_barrier" ::: "memory")
#define WAIT_VM6() asm volatile("s_waitcnt vmcnt(6)" ::: "memory")
#define WAIT_VM0() asm volatile("s_waitcnt vmcnt(0)" ::: "memory")

// ---------------- f32 -> bf16 conversion (8 elems/thread) ----------------
__global__ __launch_bounds__(256) void cvt_f2bf(const float* __restrict__ in,
                                                unsigned short* __restrict__ out,
                                                int n8) {
    int i = blockIdx.x * 256 + threadIdx.x;
    if (i >= n8) return;
    floatx4 a = ((const floatx4*)in)[2 * i];
    floatx4 b = ((const floatx4*)in)[2 * i + 1];
    ushort8 o;
#pragma unroll
    for (int j = 0; j < 4; ++j) { o[j] = f2bf(a[j]); o[4 + j] = f2bf(b[j]); }
    ((ushort8*)out)[i] = o;
}

// ---------------- Weff[o][j] = g[j]*fcW[o][j] + g[j+2048]*fcW[o][j+2048] ----
__global__ __launch_bounds__(256) void weff_kernel(const float* __restrict__ fcW,
                                                   const float* __restrict__ lng,
                                                   const float* __restrict__ lnb,
                                                   const float* __restrict__ fcb,
                                                   unsigned short* __restrict__ weff,
                                                   float* __restrict__ cc) {
    int o = blockIdx.x;
    int tid = threadIdx.x;
    if (o >= 1000) {
        ushort8 z = {0, 0, 0, 0, 0, 0, 0, 0};
        ((ushort8*)(weff + (size_t)o * 2048))[tid] = z;
        if (tid == 0) cc[o] = 0.f;
        return;
    }
    const float* wrow = fcW + (size_t)o * 4096;
    int j0 = tid * 8;
    floatx4 wa  = *(const floatx4*)(wrow + j0);
    floatx4 wb  = *(const floatx4*)(wrow + j0 + 4);
    floatx4 wa2 = *(const floatx4*)(wrow + 2048 + j0);
    floatx4 wb2 = *(const floatx4*)(wrow + 2048 + j0 + 4);
    floatx4 ga  = *(const floatx4*)(lng + j0);
    floatx4 gb  = *(const floatx4*)(lng + j0 + 4);
    floatx4 ga2 = *(const floatx4*)(lng + 2048 + j0);
    floatx4 gb2 = *(const floatx4*)(lng + 2048 + j0 + 4);
    floatx4 ba  = *(const floatx4*)(lnb + j0);
    floatx4 bb  = *(const floatx4*)(lnb + j0 + 4);
    floatx4 ba2 = *(const floatx4*)(lnb + 2048 + j0);
    floatx4 bb2 = *(const floatx4*)(lnb + 2048 + j0 + 4);
    ushort8 o8;
    float acc = 0.f;
#pragma unroll
    for (int j = 0; j < 4; ++j) {
        o8[j] = f2bf(ga[j] * wa[j] + ga2[j] * wa2[j]);
        acc += ba[j] * wa[j] + ba2[j] * wa2[j];
        o8[4 + j] = f2bf(gb[j] * wb[j] + gb2[j] * wb2[j]);
        acc += bb[j] * wb[j] + bb2[j] * wb2[j];
    }
    ((ushort8*)(weff + (size_t)o * 2048))[tid] = o8;
#pragma unroll
    for (int d = 32; d; d >>= 1) acc += __shfl_down(acc, d);
    __shared__ float red[4];
    if ((tid & 63) == 0) red[tid >> 6] = acc;
    __syncthreads();
    if (tid == 0) cc[o] = fcb[o] + red[0] + red[1] + red[2] + red[3];
}

// ---------------- row LayerNorm: z = (h2-mu)*rsqrt(var+eps) ---------------
__global__ __launch_bounds__(256) void ln_kernel(const unsigned short* __restrict__ h2,
                                                 unsigned short* __restrict__ z) {
    int row = blockIdx.x, tid = threadIdx.x;
    ushort8 v = ((const ushort8*)(h2 + (size_t)row * 2048))[tid];
    float f[8];
    float s = 0.f, s2 = 0.f;
#pragma unroll
    for (int j = 0; j < 8; ++j) { f[j] = bf2f(v[j]); s += f[j]; s2 += f[j] * f[j]; }
#pragma unroll
    for (int d = 32; d; d >>= 1) { s += __shfl_down(s, d); s2 += __shfl_down(s2, d); }
    __shared__ float rs_[4], rs2_[4];
    if ((tid & 63) == 0) { rs_[tid >> 6] = s; rs2_[tid >> 6] = s2; }
    __syncthreads();
    float S = rs_[0] + rs_[1] + rs_[2] + rs_[3];
    float S2 = rs2_[0] + rs2_[1] + rs2_[2] + rs2_[3];
    float mu = S * (1.f / 2048.f);
    float var = S2 * (1.f / 2048.f) - mu * mu;
    float r = rsqrtf(var + 1e-5f);
    ushort8 o;
#pragma unroll
    for (int j = 0; j < 8; ++j) o[j] = f2bf((f[j] - mu) * r);
    ((ushort8*)(z + (size_t)row * 2048))[tid] = o;
}

// ============ 8-phase-style bf16 GEMM: C[M,N] = A[M,K]*B[N,K]^T ============
// BM=128, BN=256, BK=64, 512 threads (8 waves: 2M x 4N), per-wave C = 64x64.
// Triple-buffered LDS (3 x 48KB), depth-2 prefetch, counted vmcnt(6),
// XOR-swizzled LDS (byte ^= (row&7)<<4) via pre-swizzled global source.
// EPI 0: bf16 out = tanh(acc + bias0[n] + bias1[n]), stride N
// EPI 1: f32 out = acc + bias0[n], stride ncols, guarded col < ncols
template <int EPI>
__global__ __launch_bounds__(512, 2) void gemm8p(const unsigned short* __restrict__ A,
                                                 const unsigned short* __restrict__ B,
                                                 int M, int N, int K,
                                                 const float* __restrict__ bias0,
                                                 const float* __restrict__ bias1,
                                                 void* __restrict__ Cout, int ncols) {
    extern __shared__ char smem[];
    const int tid = threadIdx.x;
    const int lane = tid & 63, wid = tid >> 6;
    const int wm = wid >> 2, wn = wid & 3;      // 2 x 4 wave grid
    const int fr = lane & 15, g = lane >> 4;

    // XCD-aware bijective swizzle (nwg % 8 == 0 for all our launches)
    const int nwg = gridDim.x * gridDim.y;
    const int fid = blockIdx.y * gridDim.x + blockIdx.x;
    const int cpx = nwg >> 3;
    const int sw = (fid & 7) * cpx + (fid >> 3);
    const int bx = sw % gridDim.x, by = sw / gridDim.x;
    const int row0 = by * 128, col0 = bx * 256;

    // staging: thread t covers dest byte d = round*8192 + t*16 (linear LDS).
    // logical row = d>>7, col-byte = (d&127) ^ ((row&7)<<4)  (involution)
    const int tg = tid >> 3;                              // row within 64-row round
    const int tcE = ((tid & 7) ^ (tg & 7)) * 8;           // element offset in row

    auto stageA = [&](int kt, char* buf) {
#pragma unroll
        for (int r = 0; r < 2; ++r)
            gload_lds16(A + (size_t)(row0 + r * 64 + tg) * K + kt * 64 + tcE,
                        buf + r * 8192 + wid * 1024);
    };
    auto stageBh = [&](int kt, char* buf, int h) {
#pragma unroll
        for (int r = 0; r < 2; ++r) {
            int rr = h * 2 + r;
            gload_lds16(B + (size_t)(col0 + rr * 64 + tg) * K + kt * 64 + tcE,
                        buf + 16384 + rr * 8192 + wid * 1024);
        }
    };

    // swizzled fragment reads
    const int xorv = (fr & 7) << 4;
    auto rdA = [&](const char* buf, int m, int kh) -> bf16x8 {
        int byte = (wm * 64 + m * 16 + fr) * 128 + ((kh * 64 + g * 16) ^ xorv);
        return __builtin_bit_cast(bf16x8, *(const ushort8*)(buf + byte));
    };
    auto rdB = [&](const char* buf, int n, int kh) -> bf16x8 {
        int byte = 16384 + (wn * 64 + n * 16 + fr) * 128 + ((kh * 64 + g * 16) ^ xorv);
        return __builtin_bit_cast(bf16x8, *(const ushort8*)(buf + byte));
    };

    f32x4 acc[4][4];
#pragma unroll
    for (int i = 0; i < 4; ++i)
#pragma unroll
        for (int j = 0; j < 4; ++j) acc[i][j] = f32x4{0.f, 0.f, 0.f, 0.f};

    char* b0 = smem;
    char* b1 = smem + 49152;
    // prologue: stage tiles 0 and 1
    stageA(0, b0); stageBh(0, b0, 0); stageBh(0, b0, 1);
    stageA(1, b1); stageBh(1, b1, 0); stageBh(1, b1, 1);
    WAIT_VM6();   // tile 0 landed, tile 1 in flight
    BAR();

    const int NT = K >> 6;
    bf16x8 aF[2][2], bF0[2][2], bF1[2][2];
    for (int t = 0; t < NT; ++t) {
        char* rb = smem + (t % 3) * 49152;
        char* wb = smem + ((t + 2) % 3) * 49152;
        const bool st = (t + 2) < NT;

        // ---- phase 0: read A(m0,m1)+B(n0,n1), stage next A ----
#pragma unroll
        for (int i = 0; i < 2; ++i)
#pragma unroll
            for (int kh = 0; kh < 2; ++kh) {
                aF[i][kh] = rdA(rb, i, kh);
                bF0[i][kh] = rdB(rb, i, kh);
            }
        if (st) stageA(t + 2, wb);
        BAR();
        __builtin_amdgcn_s_setprio(1);
#pragma unroll
        for (int i = 0; i < 2; ++i)
#pragma unroll
            for (int j = 0; j < 2; ++j)
#pragma unroll
                for (int kh = 0; kh < 2; ++kh)
                    acc[i][j] = __builtin_amdgcn_mfma_f32_16x16x32_bf16(aF[i][kh], bF0[j][kh], acc[i][j], 0, 0, 0);
        __builtin_amdgcn_s_setprio(0);
        BAR();

        // ---- phase 1: read B(n2,n3), stage next B half 0 ----
#pragma unroll
        for (int j = 0; j < 2; ++j)
#pragma unroll
            for (int kh = 0; kh < 2; ++kh) bF1[j][kh] = rdB(rb, 2 + j, kh);
        if (st) stageBh(t + 2, wb, 0);
        BAR();
        __builtin_amdgcn_s_setprio(1);
#pragma unroll
        for (int i = 0; i < 2; ++i)
#pragma unroll
            for (int j = 0; j < 2; ++j)
#pragma unroll
                for (int kh = 0; kh < 2; ++kh)
                    acc[i][2 + j] = __builtin_amdgcn_mfma_f32_16x16x32_bf16(aF[i][kh], bF1[j][kh], acc[i][2 + j], 0, 0, 0);
        __builtin_amdgcn_s_setprio(0);
        BAR();

        // ---- phase 2: read A(m2,m3), stage next B half 1 ----
#pragma unroll
        for (int i = 0; i < 2; ++i)
#pragma unroll
            for (int kh = 0; kh < 2; ++kh) aF[i][kh] = rdA(rb, 2 + i, kh);
        if (st) stageBh(t + 2, wb, 1);
        BAR();
        __builtin_amdgcn_s_setprio(1);
#pragma unroll
        for (int i = 0; i < 2; ++i)
#pragma unroll
            for (int j = 0; j < 2; ++j)
#pragma unroll
                for (int kh = 0; kh < 2; ++kh)
                    acc[2 + i][2 + j] = __builtin_amdgcn_mfma_f32_16x16x32_bf16(aF[i][kh], bF1[j][kh], acc[2 + i][2 + j], 0, 0, 0);
        __builtin_amdgcn_s_setprio(0);
        BAR();

        // ---- phase 3: no reads; MFMA A(m2,m3) x B(n0,n1); per-tile vmcnt ----
        __builtin_amdgcn_s_setprio(1);
#pragma unroll
        for (int i = 0; i < 2; ++i)
#pragma unroll
            for (int j = 0; j < 2; ++j)
#pragma unroll
                for (int kh = 0; kh < 2; ++kh)
                    acc[2 + i][j] = __builtin_amdgcn_mfma_f32_16x16x32_bf16(aF[i][kh], bF0[j][kh], acc[2 + i][j], 0, 0, 0);
        __builtin_amdgcn_s_setprio(0);
        if (st) { WAIT_VM6(); }           // keep next tile's 6 loads in flight
        else if (t + 1 < NT) { WAIT_VM0(); }
        BAR();
    }

    // ---- epilogue ----
#pragma unroll
    for (int i = 0; i < 4; ++i) {
        int rbase = row0 + wm * 64 + i * 16 + g * 4;
#pragma unroll
        for (int j = 0; j < 4; ++j) {
            int col = col0 + wn * 64 + j * 16 + fr;
            if (EPI == 0) {
                float bsum = bias0[col] + bias1[col];
                unsigned short* O = (unsigned short*)Cout;
#pragma unroll
                for (int r = 0; r < 4; ++r)
                    O[(size_t)(rbase + r) * N + col] = f2bf(tanhf(acc[i][j][r] + bsum));
            } else {
                if (col < ncols) {
                    float bsum = bias0[col];
                    float* O = (float*)Cout;
#pragma unroll
                    for (int r = 0; r < 4; ++r)
                        O[(size_t)(rbase + r) * ncols + col] = acc[i][j][r] + bsum;
                }
            }
        }
    }
}

extern "C" void kernel_launch(void* const* d_in, const int* in_sizes, int n_in,
                              void* d_out, int out_size, void* d_ws, size_t ws_size,
                              hipStream_t stream) {
    const float* x   = (const float*)d_in[0];
    const float* W0  = (const float*)d_in[1];
    const float* bi0 = (const float*)d_in[2];
    const float* bh0 = (const float*)d_in[3];
    const float* W1  = (const float*)d_in[4];
    const float* bi1 = (const float*)d_in[5];
    const float* bh1 = (const float*)d_in[6];
    const float* lng = (const float*)d_in[7];
    const float* lnb = (const float*)d_in[8];
    const float* fcW = (const float*)d_in[9];
    const float* fcb = (const float*)d_in[10];
    float* out = (float*)d_out;

    char* w = (char*)d_ws;
    unsigned short* xb   = (unsigned short*)(w);                  // 4096x4096 bf16
    unsigned short* w0b  = (unsigned short*)(w + 33554432ull);    // 2048x4096 bf16
    unsigned short* w1b  = (unsigned short*)(w + 50331648ull);    // 2048x2048 bf16
    unsigned short* h1   = (unsigned short*)(w + 58720256ull);    // 4096x2048 bf16
    unsigned short* h2   = (unsigned short*)(w + 75497472ull);    // 4096x2048 bf16
    unsigned short* zb   = (unsigned short*)(w + 92274688ull);    // 4096x2048 bf16
    unsigned short* weff = (unsigned short*)(w + 109051904ull);   // 1024x2048 bf16
    float* cc            = (float*)(w + 113246208ull);            // 1024 f32

    const int SHM = 147456;  // 3 x (16KB A + 32KB B)
    (void)hipFuncSetAttribute((const void*)gemm8p<0>,
                              hipFuncAttributeMaxDynamicSharedMemorySize, SHM);
    (void)hipFuncSetAttribute((const void*)gemm8p<1>,
                              hipFuncAttributeMaxDynamicSharedMemorySize, SHM);

    cvt_f2bf<<<8192, 256, 0, stream>>>(x,  xb,  2097152);
    cvt_f2bf<<<4096, 256, 0, stream>>>(W0, w0b, 1048576);
    cvt_f2bf<<<2048, 256, 0, stream>>>(W1, w1b, 524288);
    weff_kernel<<<1024, 256, 0, stream>>>(fcW, lng, lnb, fcb, weff, cc);
    // h1 = tanh(x @ W0^T + b_ih0 + b_hh0)
    gemm8p<0><<<dim3(8, 32), 512, SHM, stream>>>(xb, w0b, 4096, 2048, 4096, bi0, bh0, h1, 2048);
    // h2 = tanh(h1 @ W1^T + b_ih1 + b_hh1)
    gemm8p<0><<<dim3(8, 32), 512, SHM, stream>>>(h1, w1b, 4096, 2048, 2048, bi1, bh1, h2, 2048);
    // z = (h2 - mu) * rsqrt(var + eps)
    ln_kernel<<<4096, 256, 0, stream>>>(h2, zb);
    // out = z @ Weff^T + cc   (N padded to 1024, stores guarded to 1000)
    gemm8p<1><<<dim3(4, 32), 512, SHM, stream>>>(zb, weff, 4096, 1024, 2048, cc, nullptr, out, 1000);
}

// Round 3
// 197.262 us; speedup vs baseline: 1.2084x; 1.0139x over previous
//
#include <hip/hip_runtime.h>
#include <hip/hip_bf16.h>

typedef __attribute__((ext_vector_type(8))) unsigned short ushort8;
typedef __attribute__((ext_vector_type(8))) __bf16 bf16x8;
typedef __attribute__((ext_vector_type(4))) float f32x4;
typedef __attribute__((ext_vector_type(4))) float floatx4;

__device__ __forceinline__ unsigned short f2bf(float f) {
    unsigned u = __builtin_bit_cast(unsigned, f);
    u += 0x7fffu + ((u >> 16) & 1u);   // RNE
    return (unsigned short)(u >> 16);
}
__device__ __forceinline__ float bf2f(unsigned short h) {
    unsigned u = ((unsigned)h) << 16;
    return __builtin_bit_cast(float, u);
}

__device__ __forceinline__ void gload_lds16(const void* g, void* l) {
    __builtin_amdgcn_global_load_lds(
        (const __attribute__((address_space(1))) void*)g,
        (__attribute__((address_space(3))) void*)l,
        16, 0, 0);
}

#define BAR()      asm volatile("s_barrier" ::: "memory")
#define WAIT_VM6() asm volatile("s_waitcnt vmcnt(6)" ::: "memory")
#define WAIT_VM0() asm volatile("s_waitcnt vmcnt(0)" ::: "memory")

// ---------------- f32 -> bf16 conversion (8 elems/thread) ----------------
__global__ __launch_bounds__(256) void cvt_f2bf(const float* __restrict__ in,
                                                unsigned short* __restrict__ out,
                                                int n8) {
    int i = blockIdx.x * 256 + threadIdx.x;
    if (i >= n8) return;
    floatx4 a = ((const floatx4*)in)[2 * i];
    floatx4 b = ((const floatx4*)in)[2 * i + 1];
    ushort8 o;
#pragma unroll
    for (int j = 0; j < 4; ++j) { o[j] = f2bf(a[j]); o[4 + j] = f2bf(b[j]); }
    ((ushort8*)out)[i] = o;
}

// ---------------- Weff[o][j] = g[j]*fcW[o][j] + g[j+2048]*fcW[o][j+2048] ----
__global__ __launch_bounds__(256) void weff_kernel(const float* __restrict__ fcW,
                                                   const float* __restrict__ lng,
                                                   const float* __restrict__ lnb,
                                                   const float* __restrict__ fcb,
                                                   unsigned short* __restrict__ weff,
                                                   float* __restrict__ cc) {
    int o = blockIdx.x;
    int tid = threadIdx.x;
    if (o >= 1000) {
        ushort8 z = {0, 0, 0, 0, 0, 0, 0, 0};
        ((ushort8*)(weff + (size_t)o * 2048))[tid] = z;
        if (tid == 0) cc[o] = 0.f;
        return;
    }
    const float* wrow = fcW + (size_t)o * 4096;
    int j0 = tid * 8;
    floatx4 wa  = *(const floatx4*)(wrow + j0);
    floatx4 wb  = *(const floatx4*)(wrow + j0 + 4);
    floatx4 wa2 = *(const floatx4*)(wrow + 2048 + j0);
    floatx4 wb2 = *(const floatx4*)(wrow + 2048 + j0 + 4);
    floatx4 ga  = *(const floatx4*)(lng + j0);
    floatx4 gb  = *(const floatx4*)(lng + j0 + 4);
    floatx4 ga2 = *(const floatx4*)(lng + 2048 + j0);
    floatx4 gb2 = *(const floatx4*)(lng + 2048 + j0 + 4);
    floatx4 ba  = *(const floatx4*)(lnb + j0);
    floatx4 bb  = *(const floatx4*)(lnb + j0 + 4);
    floatx4 ba2 = *(const floatx4*)(lnb + 2048 + j0);
    floatx4 bb2 = *(const floatx4*)(lnb + 2048 + j0 + 4);
    ushort8 o8;
    float acc = 0.f;
#pragma unroll
    for (int j = 0; j < 4; ++j) {
        o8[j] = f2bf(ga[j] * wa[j] + ga2[j] * wa2[j]);
        acc += ba[j] * wa[j] + ba2[j] * wa2[j];
        o8[4 + j] = f2bf(gb[j] * wb[j] + gb2[j] * wb2[j]);
        acc += bb[j] * wb[j] + bb2[j] * wb2[j];
    }
    ((ushort8*)(weff + (size_t)o * 2048))[tid] = o8;
#pragma unroll
    for (int d = 32; d; d >>= 1) acc += __shfl_down(acc, d);
    __shared__ float red[4];
    if ((tid & 63) == 0) red[tid >> 6] = acc;
    __syncthreads();
    if (tid == 0) cc[o] = fcb[o] + red[0] + red[1] + red[2] + red[3];
}

// ---------------- row LayerNorm: z = (h2-mu)*rsqrt(var+eps) ---------------
__global__ __launch_bounds__(256) void ln_kernel(const unsigned short* __restrict__ h2,
                                                 unsigned short* __restrict__ z) {
    int row = blockIdx.x, tid = threadIdx.x;
    ushort8 v = ((const ushort8*)(h2 + (size_t)row * 2048))[tid];
    float f[8];
    float s = 0.f, s2 = 0.f;
#pragma unroll
    for (int j = 0; j < 8; ++j) { f[j] = bf2f(v[j]); s += f[j]; s2 += f[j] * f[j]; }
#pragma unroll
    for (int d = 32; d; d >>= 1) { s += __shfl_down(s, d); s2 += __shfl_down(s2, d); }
    __shared__ float rs_[4], rs2_[4];
    if ((tid & 63) == 0) { rs_[tid >> 6] = s; rs2_[tid >> 6] = s2; }
    __syncthreads();
    float S = rs_[0] + rs_[1] + rs_[2] + rs_[3];
    float S2 = rs2_[0] + rs2_[1] + rs2_[2] + rs2_[3];
    float mu = S * (1.f / 2048.f);
    float var = S2 * (1.f / 2048.f) - mu * mu;
    float r = rsqrtf(var + 1e-5f);
    ushort8 o;
#pragma unroll
    for (int j = 0; j < 8; ++j) o[j] = f2bf((f[j] - mu) * r);
    ((ushort8*)(z + (size_t)row * 2048))[tid] = o;
}

// ============ 2-phase/K-tile bf16 GEMM: C[M,N] = A[M,K]*B[N,K]^T ===========
// BM=128, BN=256, BK=64, 512 threads (8 waves: 2M x 4N), per-wave C = 64x64.
// Triple-buffered LDS (3 x 48KB), depth-2 prefetch, counted vmcnt(6),
// XOR-swizzled LDS (byte ^= (row&7)<<4) via pre-swizzled global source.
// Per K-tile: 2 phases, each {ds_reads + stage -> barrier -> 16-MFMA burst}.
// EPI 0: bf16 out = tanh(acc + bias0[n] + bias1[n]), stride N
// EPI 1: f32 out = acc + bias0[n], stride ncols, guarded col < ncols
template <int EPI>
__global__ __launch_bounds__(512, 2) void gemm8p(const unsigned short* __restrict__ A,
                                                 const unsigned short* __restrict__ B,
                                                 int M, int N, int K,
                                                 const float* __restrict__ bias0,
                                                 const float* __restrict__ bias1,
                                                 void* __restrict__ Cout, int ncols) {
    extern __shared__ char smem[];
    const int tid = threadIdx.x;
    const int lane = tid & 63, wid = tid >> 6;
    const int wm = wid >> 2, wn = wid & 3;      // 2 x 4 wave grid
    const int fr = lane & 15, g = lane >> 4;

    // XCD-aware bijective swizzle (nwg % 8 == 0 for all our launches)
    const int nwg = gridDim.x * gridDim.y;
    const int fid = blockIdx.y * gridDim.x + blockIdx.x;
    const int cpx = nwg >> 3;
    const int sw = (fid & 7) * cpx + (fid >> 3);
    const int bx = sw % gridDim.x, by = sw / gridDim.x;
    const int row0 = by * 128, col0 = bx * 256;

    // staging: thread t covers dest byte d = round*8192 + t*16 (linear LDS).
    // logical row = d>>7, col-byte = (d&127) ^ ((row&7)<<4)  (involution)
    const int tg = tid >> 3;                              // row within 64-row round
    const int tcE = ((tid & 7) ^ (tg & 7)) * 8;           // element offset in row

    auto stageA = [&](int kt, char* buf) {
#pragma unroll
        for (int r = 0; r < 2; ++r)
            gload_lds16(A + (size_t)(row0 + r * 64 + tg) * K + kt * 64 + tcE,
                        buf + r * 8192 + wid * 1024);
    };
    auto stageBh = [&](int kt, char* buf, int h) {
#pragma unroll
        for (int r = 0; r < 2; ++r) {
            int rr = h * 2 + r;
            gload_lds16(B + (size_t)(col0 + rr * 64 + tg) * K + kt * 64 + tcE,
                        buf + 16384 + rr * 8192 + wid * 1024);
        }
    };

    // swizzled fragment reads
    const int xorv = (fr & 7) << 4;
    auto rdA = [&](const char* buf, int m, int kh) -> bf16x8 {
        int byte = (wm * 64 + m * 16 + fr) * 128 + ((kh * 64 + g * 16) ^ xorv);
        return __builtin_bit_cast(bf16x8, *(const ushort8*)(buf + byte));
    };
    auto rdB = [&](const char* buf, int n, int kh) -> bf16x8 {
        int byte = 16384 + (wn * 64 + n * 16 + fr) * 128 + ((kh * 64 + g * 16) ^ xorv);
        return __builtin_bit_cast(bf16x8, *(const ushort8*)(buf + byte));
    };

    f32x4 acc[4][4];
#pragma unroll
    for (int i = 0; i < 4; ++i)
#pragma unroll
        for (int j = 0; j < 4; ++j) acc[i][j] = f32x4{0.f, 0.f, 0.f, 0.f};

    char* b0 = smem;
    char* b1 = smem + 49152;
    // prologue: stage tiles 0 and 1
    stageA(0, b0); stageBh(0, b0, 0); stageBh(0, b0, 1);
    stageA(1, b1); stageBh(1, b1, 0); stageBh(1, b1, 1);
    WAIT_VM6();   // tile 0 landed, tile 1 in flight
    BAR();

    const int NT = K >> 6;
    bf16x8 aF[4][2], bF[2][2];
    for (int t = 0; t < NT; ++t) {
        char* rb = smem + (t % 3) * 49152;
        char* wb = smem + ((t + 2) % 3) * 49152;
        const bool st = (t + 2) < NT;

        // ---- phase A: read B(n0,n1) + all A; stage next A + B-half0 ----
#pragma unroll
        for (int j = 0; j < 2; ++j)
#pragma unroll
            for (int kh = 0; kh < 2; ++kh) bF[j][kh] = rdB(rb, j, kh);
#pragma unroll
        for (int m = 0; m < 4; ++m)
#pragma unroll
            for (int kh = 0; kh < 2; ++kh) aF[m][kh] = rdA(rb, m, kh);
        if (st) { stageA(t + 2, wb); stageBh(t + 2, wb, 0); }
        BAR();
        __builtin_amdgcn_s_setprio(1);
#pragma unroll
        for (int m = 0; m < 4; ++m)
#pragma unroll
            for (int j = 0; j < 2; ++j)
#pragma unroll
                for (int kh = 0; kh < 2; ++kh)
                    acc[m][j] = __builtin_amdgcn_mfma_f32_16x16x32_bf16(aF[m][kh], bF[j][kh], acc[m][j], 0, 0, 0);
        __builtin_amdgcn_s_setprio(0);
        BAR();

        // ---- phase B: read B(n2,n3); stage next B-half1 ----
#pragma unroll
        for (int j = 0; j < 2; ++j)
#pragma unroll
            for (int kh = 0; kh < 2; ++kh) bF[j][kh] = rdB(rb, 2 + j, kh);
        if (st) stageBh(t + 2, wb, 1);
        BAR();
        __builtin_amdgcn_s_setprio(1);
#pragma unroll
        for (int m = 0; m < 4; ++m)
#pragma unroll
            for (int j = 0; j < 2; ++j)
#pragma unroll
                for (int kh = 0; kh < 2; ++kh)
                    acc[m][2 + j] = __builtin_amdgcn_mfma_f32_16x16x32_bf16(aF[m][kh], bF[j][kh], acc[m][2 + j], 0, 0, 0);
        __builtin_amdgcn_s_setprio(0);
        if (st) { WAIT_VM6(); }           // keep next tile's 6 loads in flight
        else if (t + 1 < NT) { WAIT_VM0(); }
        BAR();
    }

    // ---- epilogue ----
#pragma unroll
    for (int i = 0; i < 4; ++i) {
        int rbase = row0 + wm * 64 + i * 16 + g * 4;
#pragma unroll
        for (int j = 0; j < 4; ++j) {
            int col = col0 + wn * 64 + j * 16 + fr;
            if (EPI == 0) {
                float bsum = bias0[col] + bias1[col];
                unsigned short* O = (unsigned short*)Cout;
#pragma unroll
                for (int r = 0; r < 4; ++r)
                    O[(size_t)(rbase + r) * N + col] = f2bf(tanhf(acc[i][j][r] + bsum));
            } else {
                if (col < ncols) {
                    float bsum = bias0[col];
                    float* O = (float*)Cout;
#pragma unroll
                    for (int r = 0; r < 4; ++r)
                        O[(size_t)(rbase + r) * ncols + col] = acc[i][j][r] + bsum;
                }
            }
        }
    }
}

extern "C" void kernel_launch(void* const* d_in, const int* in_sizes, int n_in,
                              void* d_out, int out_size, void* d_ws, size_t ws_size,
                              hipStream_t stream) {
    const float* x   = (const float*)d_in[0];
    const float* W0  = (const float*)d_in[1];
    const float* bi0 = (const float*)d_in[2];
    const float* bh0 = (const float*)d_in[3];
    const float* W1  = (const float*)d_in[4];
    const float* bi1 = (const float*)d_in[5];
    const float* bh1 = (const float*)d_in[6];
    const float* lng = (const float*)d_in[7];
    const float* lnb = (const float*)d_in[8];
    const float* fcW = (const float*)d_in[9];
    const float* fcb = (const float*)d_in[10];
    float* out = (float*)d_out;

    char* w = (char*)d_ws;
    unsigned short* xb   = (unsigned short*)(w);                  // 4096x4096 bf16
    unsigned short* w0b  = (unsigned short*)(w + 33554432ull);    // 2048x4096 bf16
    unsigned short* w1b  = (unsigned short*)(w + 50331648ull);    // 2048x2048 bf16
    unsigned short* h1   = (unsigned short*)(w + 58720256ull);    // 4096x2048 bf16
    unsigned short* h2   = (unsigned short*)(w + 75497472ull);    // 4096x2048 bf16
    unsigned short* zb   = (unsigned short*)(w + 92274688ull);    // 4096x2048 bf16
    unsigned short* weff = (unsigned short*)(w + 109051904ull);   // 1024x2048 bf16
    float* cc            = (float*)(w + 113246208ull);            // 1024 f32

    const int SHM = 147456;  // 3 x (16KB A + 32KB B)
    (void)hipFuncSetAttribute((const void*)gemm8p<0>,
                              hipFuncAttributeMaxDynamicSharedMemorySize, SHM);
    (void)hipFuncSetAttribute((const void*)gemm8p<1>,
                              hipFuncAttributeMaxDynamicSharedMemorySize, SHM);

    cvt_f2bf<<<8192, 256, 0, stream>>>(x,  xb,  2097152);
    cvt_f2bf<<<4096, 256, 0, stream>>>(W0, w0b, 1048576);
    cvt_f2bf<<<2048, 256, 0, stream>>>(W1, w1b, 524288);
    weff_kernel<<<1024, 256, 0, stream>>>(fcW, lng, lnb, fcb, weff, cc);
    // h1 = tanh(x @ W0^T + b_ih0 + b_hh0)
    gemm8p<0><<<dim3(8, 32), 512, SHM, stream>>>(xb, w0b, 4096, 2048, 4096, bi0, bh0, h1, 2048);
    // h2 = tanh(h1 @ W1^T + b_ih1 + b_hh1)
    gemm8p<0><<<dim3(8, 32), 512, SHM, stream>>>(h1, w1b, 4096, 2048, 2048, bi1, bh1, h2, 2048);
    // z = (h2 - mu) * rsqrt(var + eps)
    ln_kernel<<<4096, 256, 0, stream>>>(h2, zb);
    // out = z @ Weff^T + cc   (N padded to 1024, stores guarded to 1000)
    gemm8p<1><<<dim3(4, 32), 512, SHM, stream>>>(zb, weff, 4096, 1024, 2048, cc, nullptr, out, 1000);
}

// Round 4
// 174.175 us; speedup vs baseline: 1.3685x; 1.1326x over previous
//
#include <hip/hip_runtime.h>
#include <hip/hip_bf16.h>

typedef __attribute__((ext_vector_type(8))) unsigned short ushort8;
typedef __attribute__((ext_vector_type(8))) __bf16 bf16x8;
typedef __attribute__((ext_vector_type(4))) float f32x4;
typedef __attribute__((ext_vector_type(4))) float floatx4;

__device__ __forceinline__ unsigned short f2bf(float f) {
    unsigned u = __builtin_bit_cast(unsigned, f);
    u += 0x7fffu + ((u >> 16) & 1u);   // RNE
    return (unsigned short)(u >> 16);
}
__device__ __forceinline__ float bf2f(unsigned short h) {
    unsigned u = ((unsigned)h) << 16;
    return __builtin_bit_cast(float, u);
}

__device__ __forceinline__ void gload_lds16(const void* g, void* l) {
    __builtin_amdgcn_global_load_lds(
        (const __attribute__((address_space(1))) void*)g,
        (__attribute__((address_space(3))) void*)l,
        16, 0, 0);
}

#define BAR()      asm volatile("s_barrier" ::: "memory")

// ---------------- f32 -> bf16 conversion (8 elems/thread) ----------------
__global__ __launch_bounds__(256) void cvt_f2bf(const float* __restrict__ in,
                                                unsigned short* __restrict__ out,
                                                int n8) {
    int i = blockIdx.x * 256 + threadIdx.x;
    if (i >= n8) return;
    floatx4 a = ((const floatx4*)in)[2 * i];
    floatx4 b = ((const floatx4*)in)[2 * i + 1];
    ushort8 o;
#pragma unroll
    for (int j = 0; j < 4; ++j) { o[j] = f2bf(a[j]); o[4 + j] = f2bf(b[j]); }
    ((ushort8*)out)[i] = o;
}

// ---------------- Weff[o][j] = g[j]*fcW[o][j] + g[j+2048]*fcW[o][j+2048] ----
__global__ __launch_bounds__(256) void weff_kernel(const float* __restrict__ fcW,
                                                   const float* __restrict__ lng,
                                                   const float* __restrict__ lnb,
                                                   const float* __restrict__ fcb,
                                                   unsigned short* __restrict__ weff,
                                                   float* __restrict__ cc) {
    int o = blockIdx.x;
    int tid = threadIdx.x;
    if (o >= 1000) {
        ushort8 z = {0, 0, 0, 0, 0, 0, 0, 0};
        ((ushort8*)(weff + (size_t)o * 2048))[tid] = z;
        if (tid == 0) cc[o] = 0.f;
        return;
    }
    const float* wrow = fcW + (size_t)o * 4096;
    int j0 = tid * 8;
    floatx4 wa  = *(const floatx4*)(wrow + j0);
    floatx4 wb  = *(const floatx4*)(wrow + j0 + 4);
    floatx4 wa2 = *(const floatx4*)(wrow + 2048 + j0);
    floatx4 wb2 = *(const floatx4*)(wrow + 2048 + j0 + 4);
    floatx4 ga  = *(const floatx4*)(lng + j0);
    floatx4 gb  = *(const floatx4*)(lng + j0 + 4);
    floatx4 ga2 = *(const floatx4*)(lng + 2048 + j0);
    floatx4 gb2 = *(const floatx4*)(lng + 2048 + j0 + 4);
    floatx4 ba  = *(const floatx4*)(lnb + j0);
    floatx4 bb  = *(const floatx4*)(lnb + j0 + 4);
    floatx4 ba2 = *(const floatx4*)(lnb + 2048 + j0);
    floatx4 bb2 = *(const floatx4*)(lnb + 2048 + j0 + 4);
    ushort8 o8;
    float acc = 0.f;
#pragma unroll
    for (int j = 0; j < 4; ++j) {
        o8[j] = f2bf(ga[j] * wa[j] + ga2[j] * wa2[j]);
        acc += ba[j] * wa[j] + ba2[j] * wa2[j];
        o8[4 + j] = f2bf(gb[j] * wb[j] + gb2[j] * wb2[j]);
        acc += bb[j] * wb[j] + bb2[j] * wb2[j];
    }
    ((ushort8*)(weff + (size_t)o * 2048))[tid] = o8;
#pragma unroll
    for (int d = 32; d; d >>= 1) acc += __shfl_down(acc, d);
    __shared__ float red[4];
    if ((tid & 63) == 0) red[tid >> 6] = acc;
    __syncthreads();
    if (tid == 0) cc[o] = fcb[o] + red[0] + red[1] + red[2] + red[3];
}

// ---------------- row LayerNorm: z = (h2-mu)*rsqrt(var+eps) ---------------
__global__ __launch_bounds__(256) void ln_kernel(const unsigned short* __restrict__ h2,
                                                 unsigned short* __restrict__ z) {
    int row = blockIdx.x, tid = threadIdx.x;
    ushort8 v = ((const ushort8*)(h2 + (size_t)row * 2048))[tid];
    float f[8];
    float s = 0.f, s2 = 0.f;
#pragma unroll
    for (int j = 0; j < 8; ++j) { f[j] = bf2f(v[j]); s += f[j]; s2 += f[j] * f[j]; }
#pragma unroll
    for (int d = 32; d; d >>= 1) { s += __shfl_down(s, d); s2 += __shfl_down(s2, d); }
    __shared__ float rs_[4], rs2_[4];
    if ((tid & 63) == 0) { rs_[tid >> 6] = s; rs2_[tid >> 6] = s2; }
    __syncthreads();
    float S = rs_[0] + rs_[1] + rs_[2] + rs_[3];
    float S2 = rs2_[0] + rs2_[1] + rs2_[2] + rs2_[3];
    float mu = S * (1.f / 2048.f);
    float var = S2 * (1.f / 2048.f) - mu * mu;
    float r = rsqrtf(var + 1e-5f);
    ushort8 o;
#pragma unroll
    for (int j = 0; j < 8; ++j) o[j] = f2bf((f[j] - mu) * r);
    ((ushort8*)(z + (size_t)row * 2048))[tid] = o;
}

// ====== free-run bf16 GEMM: C[M,N] = A[M,K]*B[N,K]^T, 1 barrier/K-tile =====
// BM=128, BN=64*NJ, BK=64, 512 threads (8 waves: 2M x 4N), per-wave 64 x 16*NJ.
// Triple-buffered LDS, depth-2 prefetch, counted vmcnt (never 0 in steady),
// XOR-swizzled LDS (byte ^= (row&7)<<4) via pre-swizzled global source.
// Per K-tile: vmcnt -> s_barrier -> stage(t+2) -> ds_reads + MFMAs free-run.
// EPI 0: bf16 out = tanh(acc + bias0[n] + bias1[n]), stride N
// EPI 1: f32 out = acc + bias0[n], stride ncols, guarded col < ncols
template <int EPI, int NJ>
__global__ __launch_bounds__(512, 2) void gemm_fr(const unsigned short* __restrict__ A,
                                                  const unsigned short* __restrict__ B,
                                                  int M, int N, int K,
                                                  const float* __restrict__ bias0,
                                                  const float* __restrict__ bias1,
                                                  void* __restrict__ Cout, int ncols) {
    extern __shared__ char smem[];
    constexpr int BUFSZ = 16384 + NJ * 8192;   // A (16KB) + B (NJ*8KB)
    const int tid = threadIdx.x;
    const int lane = tid & 63, wid = tid >> 6;
    const int wm = wid >> 2, wn = wid & 3;      // 2 x 4 wave grid
    const int fr = lane & 15, g = lane >> 4;

    // XCD-aware bijective swizzle (nwg % 8 == 0 for all our launches)
    const int nwg = gridDim.x * gridDim.y;
    const int fid = blockIdx.y * gridDim.x + blockIdx.x;
    const int cpx = nwg >> 3;
    const int sw = (fid & 7) * cpx + (fid >> 3);
    const int bx = sw % gridDim.x, by = sw / gridDim.x;
    const int row0 = by * 128, col0 = bx * (64 * NJ);

    // staging: thread t covers dest byte d = round*8192 + t*16 (linear LDS).
    // logical row = d>>7, col-byte = (d&127) ^ ((row&7)<<4)  (involution)
    const int tg = tid >> 3;                              // row within 64-row round
    const int tcE = ((tid & 7) ^ (tg & 7)) * 8;           // element offset in row

    auto stageA = [&](int kt, char* buf) {
#pragma unroll
        for (int r = 0; r < 2; ++r)
            gload_lds16(A + (size_t)(row0 + r * 64 + tg) * K + kt * 64 + tcE,
                        buf + r * 8192 + wid * 1024);
    };
    auto stageB = [&](int kt, char* buf) {
#pragma unroll
        for (int rr = 0; rr < NJ; ++rr)
            gload_lds16(B + (size_t)(col0 + rr * 64 + tg) * K + kt * 64 + tcE,
                        buf + 16384 + rr * 8192 + wid * 1024);
    };

    // swizzled fragment reads
    const int xorv = (fr & 7) << 4;
    auto rdA = [&](const char* buf, int m, int kh) -> bf16x8 {
        int byte = (wm * 64 + m * 16 + fr) * 128 + ((kh * 64 + g * 16) ^ xorv);
        return __builtin_bit_cast(bf16x8, *(const ushort8*)(buf + byte));
    };
    auto rdB = [&](const char* buf, int n, int kh) -> bf16x8 {
        int byte = 16384 + (wn * (16 * NJ) + n * 16 + fr) * 128 + ((kh * 64 + g * 16) ^ xorv);
        return __builtin_bit_cast(bf16x8, *(const ushort8*)(buf + byte));
    };

    f32x4 acc[4][NJ];
#pragma unroll
    for (int i = 0; i < 4; ++i)
#pragma unroll
        for (int j = 0; j < NJ; ++j) acc[i][j] = f32x4{0.f, 0.f, 0.f, 0.f};

    char* p0 = smem;
    char* p1 = smem + BUFSZ;
    char* p2 = smem + 2 * BUFSZ;
    // prologue: stage tiles 0 and 1
    stageA(0, p0); stageB(0, p0);
    stageA(1, p1); stageB(1, p1);

    const int NT = K >> 6;
    for (int t = 0; t < NT; ++t) {
        char* rb = p0;
        char* wb = p2;
        // drain this tile's loads (oldest); keep next tile's in flight
        if (t < NT - 1) {
            if constexpr (NJ == 4) asm volatile("s_waitcnt vmcnt(6)" ::: "memory");
            else                   asm volatile("s_waitcnt vmcnt(4)" ::: "memory");
        } else {
            asm volatile("s_waitcnt vmcnt(0)" ::: "memory");
        }
        BAR();   // all waves' stages for tile t landed; all done reading t-1
        if (t + 2 < NT) { stageA(t + 2, wb); stageB(t + 2, wb); }

        // all fragment reads + MFMAs, compiler-scheduled (fine lgkmcnt)
        bf16x8 aF[4][2], bF[NJ][2];
#pragma unroll
        for (int m = 0; m < 4; ++m)
#pragma unroll
            for (int kh = 0; kh < 2; ++kh) aF[m][kh] = rdA(rb, m, kh);
#pragma unroll
        for (int n = 0; n < NJ; ++n)
#pragma unroll
            for (int kh = 0; kh < 2; ++kh) bF[n][kh] = rdB(rb, n, kh);

        __builtin_amdgcn_s_setprio(1);
#pragma unroll
        for (int m = 0; m < 4; ++m)
#pragma unroll
            for (int n = 0; n < NJ; ++n)
#pragma unroll
                for (int kh = 0; kh < 2; ++kh)
                    acc[m][n] = __builtin_amdgcn_mfma_f32_16x16x32_bf16(aF[m][kh], bF[n][kh], acc[m][n], 0, 0, 0);
        __builtin_amdgcn_s_setprio(0);

        // rotate buffers
        char* tmp = p0; p0 = p1; p1 = p2; p2 = tmp;
    }

    // ---- epilogue ----
#pragma unroll
    for (int i = 0; i < 4; ++i) {
        int rbase = row0 + wm * 64 + i * 16 + g * 4;
#pragma unroll
        for (int j = 0; j < NJ; ++j) {
            int col = col0 + wn * (16 * NJ) + j * 16 + fr;
            if (EPI == 0) {
                float bsum = bias0[col] + bias1[col];
                unsigned short* O = (unsigned short*)Cout;
#pragma unroll
                for (int r = 0; r < 4; ++r)
                    O[(size_t)(rbase + r) * N + col] = f2bf(tanhf(acc[i][j][r] + bsum));
            } else {
                if (col < ncols) {
                    float bsum = bias0[col];
                    float* O = (float*)Cout;
#pragma unroll
                    for (int r = 0; r < 4; ++r)
                        O[(size_t)(rbase + r) * ncols + col] = acc[i][j][r] + bsum;
                }
            }
        }
    }
}

extern "C" void kernel_launch(void* const* d_in, const int* in_sizes, int n_in,
                              void* d_out, int out_size, void* d_ws, size_t ws_size,
                              hipStream_t stream) {
    const float* x   = (const float*)d_in[0];
    const float* W0  = (const float*)d_in[1];
    const float* bi0 = (const float*)d_in[2];
    const float* bh0 = (const float*)d_in[3];
    const float* W1  = (const float*)d_in[4];
    const float* bi1 = (const float*)d_in[5];
    const float* bh1 = (const float*)d_in[6];
    const float* lng = (const float*)d_in[7];
    const float* lnb = (const float*)d_in[8];
    const float* fcW = (const float*)d_in[9];
    const float* fcb = (const float*)d_in[10];
    float* out = (float*)d_out;

    char* w = (char*)d_ws;
    unsigned short* xb   = (unsigned short*)(w);                  // 4096x4096 bf16
    unsigned short* w0b  = (unsigned short*)(w + 33554432ull);    // 2048x4096 bf16
    unsigned short* w1b  = (unsigned short*)(w + 50331648ull);    // 2048x2048 bf16
    unsigned short* h1   = (unsigned short*)(w + 58720256ull);    // 4096x2048 bf16
    unsigned short* h2   = (unsigned short*)(w + 75497472ull);    // 4096x2048 bf16
    unsigned short* zb   = (unsigned short*)(w + 92274688ull);    // 4096x2048 bf16
    unsigned short* weff = (unsigned short*)(w + 109051904ull);   // 1024x2048 bf16
    float* cc            = (float*)(w + 113246208ull);            // 1024 f32

    const int SHM0 = 3 * (16384 + 4 * 8192);  // 147456
    const int SHM1 = 3 * (16384 + 2 * 8192);  // 98304
    (void)hipFuncSetAttribute((const void*)gemm_fr<0, 4>,
                              hipFuncAttributeMaxDynamicSharedMemorySize, SHM0);
    (void)hipFuncSetAttribute((const void*)gemm_fr<1, 2>,
                              hipFuncAttributeMaxDynamicSharedMemorySize, SHM1);

    cvt_f2bf<<<8192, 256, 0, stream>>>(x,  xb,  2097152);
    cvt_f2bf<<<4096, 256, 0, stream>>>(W0, w0b, 1048576);
    cvt_f2bf<<<2048, 256, 0, stream>>>(W1, w1b, 524288);
    weff_kernel<<<1024, 256, 0, stream>>>(fcW, lng, lnb, fcb, weff, cc);
    // h1 = tanh(x @ W0^T + b_ih0 + b_hh0)
    gemm_fr<0, 4><<<dim3(8, 32), 512, SHM0, stream>>>(xb, w0b, 4096, 2048, 4096, bi0, bh0, h1, 2048);
    // h2 = tanh(h1 @ W1^T + b_ih1 + b_hh1)
    gemm_fr<0, 4><<<dim3(8, 32), 512, SHM0, stream>>>(h1, w1b, 4096, 2048, 2048, bi1, bh1, h2, 2048);
    // z = (h2 - mu) * rsqrt(var + eps)
    ln_kernel<<<4096, 256, 0, stream>>>(h2, zb);
    // out = z @ Weff^T + cc   (N padded to 1024, stores guarded to 1000)
    gemm_fr<1, 2><<<dim3(8, 32), 512, SHM1, stream>>>(zb, weff, 4096, 1024, 2048, cc, nullptr, out, 1000);
}